// Round 2
// baseline (315.453 us; speedup 1.0000x reference)
//
#include <hip/hip_runtime.h>
#include <hip/hip_bf16.h>

typedef __attribute__((ext_vector_type(8))) short short8;
typedef __attribute__((ext_vector_type(4))) float floatx4;

__device__ __forceinline__ void gload_lds16(const void* g, void* l) {
  __builtin_amdgcn_global_load_lds(
      (const __attribute__((address_space(1))) void*)g,
      (__attribute__((address_space(3))) void*)l, 16, 0, 0);
}

__device__ __forceinline__ float gelu_exact(float x) {
  return 0.5f * x * (1.0f + erff(x * 0.70710678118654752f));
}

#define BM 128
#define BN 128
#define BK 64

// C[M,N] = epilogue(A[M,K] @ B[N,K]^T + bias)   A,B bf16; bias fp32
// STORE_T: write C transposed per 4096-row batch: CT[b][col][row%4096] (bf16)
// OUT_F32: write C as float (normal layout only)
template<bool GELU_OUT, bool HASBIAS, bool STORE_T, bool OUT_F32>
__global__ __launch_bounds__(256, 2)
void gemm_nt(const __hip_bfloat16* __restrict__ Ag,
             const __hip_bfloat16* __restrict__ Bg,
             const float* __restrict__ bias,
             void* __restrict__ Cg,
             int M, int N, int K,
             long sA, long sB, long sC)
{
  const __hip_bfloat16* A = Ag + (long)blockIdx.z * sA;
  const __hip_bfloat16* B = Bg + (long)blockIdx.z * sB;

  __shared__ __align__(16) __hip_bfloat16 As[BM * BK];
  __shared__ __align__(16) __hip_bfloat16 Bs[BN * BK];

  const int tid  = threadIdx.x;
  const int lane = tid & 63;
  const int wid  = tid >> 6;   // 0..3
  const int wr   = wid >> 1;   // wave row 0..1
  const int wc   = wid & 1;    // wave col 0..1
  const int brow = blockIdx.y * BM;
  const int bcol = blockIdx.x * BN;

  floatx4 acc[4][4];
#pragma unroll
  for (int i = 0; i < 4; i++)
#pragma unroll
    for (int j = 0; j < 4; j++) acc[i][j] = (floatx4){0.f, 0.f, 0.f, 0.f};

  const int r_lo = lane >> 3;        // row within an 8-row group
  const int c8   = (lane & 7) * 8;   // k-offset (elements)

  const int ksteps = K / BK;
  for (int kt = 0; kt < ksteps; ++kt) {
    const int k0 = kt * BK;
#pragma unroll
    for (int r = 0; r < 4; ++r) {
      const int grp = r * 4 + wid;       // 16 groups of 8 rows
      const int row = grp * 8 + r_lo;
      gload_lds16(A + (size_t)(brow + row) * K + k0 + c8,
                  (void*)(As + grp * 512 + lane * 8));
      gload_lds16(B + (size_t)(bcol + row) * K + k0 + c8,
                  (void*)(Bs + grp * 512 + lane * 8));
    }
    __syncthreads();
#pragma unroll
    for (int kk = 0; kk < 2; ++kk) {
      short8 a[4], b[4];
#pragma unroll
      for (int i = 0; i < 4; i++)
        a[i] = *(const short8*)(As + (wr * 64 + i * 16 + (lane & 15)) * BK + kk * 32 + (lane >> 4) * 8);
#pragma unroll
      for (int j = 0; j < 4; j++)
        b[j] = *(const short8*)(Bs + (wc * 64 + j * 16 + (lane & 15)) * BK + kk * 32 + (lane >> 4) * 8);
#pragma unroll
      for (int i = 0; i < 4; i++)
#pragma unroll
        for (int j = 0; j < 4; j++)
          acc[i][j] = __builtin_amdgcn_mfma_f32_16x16x32_bf16(a[i], b[j], acc[i][j], 0, 0, 0);
    }
    __syncthreads();
  }

  // epilogue: C/D layout col=lane&15, row=(lane>>4)*4+reg
#pragma unroll
  for (int i = 0; i < 4; i++) {
    const int row0 = brow + wr * 64 + i * 16 + (lane >> 4) * 4;
#pragma unroll
    for (int j = 0; j < 4; j++) {
      const int col = bcol + wc * 64 + j * 16 + (lane & 15);
      float bv = 0.f;
      if (HASBIAS) bv = bias[col];
#pragma unroll
      for (int r = 0; r < 4; r++) {
        const int row = row0 + r;
        float v = acc[i][j][r] + bv;
        if (GELU_OUT) v = gelu_exact(v);
        if (OUT_F32) {
          ((float*)Cg + (long)blockIdx.z * sC)[(size_t)row * N + col] = v;
        } else if (!STORE_T) {
          ((__hip_bfloat16*)Cg + (long)blockIdx.z * sC)[(size_t)row * N + col] = __float2bfloat16(v);
        } else {
          const int bb = row >> 12;          // batch = row/4096
          const int n  = row & 4095;
          ((__hip_bfloat16*)Cg)[(size_t)bb * N * 4096 + (size_t)col * 4096 + n] = __float2bfloat16(v);
        }
      }
    }
  }
}

// fp32 -> bf16, 8 elements/thread; n must be divisible by 8
__global__ __launch_bounds__(256)
void cvt_f32_bf16(const float* __restrict__ in, __hip_bfloat16* __restrict__ out, long n) {
  long i = ((long)blockIdx.x * 256 + threadIdx.x) * 8;
  if (i >= n) return;
  float4 v0 = *(const float4*)(in + i);
  float4 v1 = *(const float4*)(in + i + 4);
  short8 o;
  __hip_bfloat16* ob = (__hip_bfloat16*)&o;
  ob[0] = __float2bfloat16(v0.x); ob[1] = __float2bfloat16(v0.y);
  ob[2] = __float2bfloat16(v0.z); ob[3] = __float2bfloat16(v0.w);
  ob[4] = __float2bfloat16(v1.x); ob[5] = __float2bfloat16(v1.y);
  ob[6] = __float2bfloat16(v1.z); ob[7] = __float2bfloat16(v1.w);
  *(short8*)(out + i) = o;
}

// Xb [B][4096][512] bf16 -> XT [B][512][4096] bf16
__global__ __launch_bounds__(256)
void transpose_xt(const __hip_bfloat16* __restrict__ in,
                  __hip_bfloat16* __restrict__ out)
{
  __shared__ __hip_bfloat16 t[64][72];
  const int b  = blockIdx.z;
  const __hip_bfloat16* I = in  + (size_t)b * 4096 * 512;
  __hip_bfloat16*       O = out + (size_t)b * 512 * 4096;
  const int n0 = blockIdx.y * 64;
  const int d0 = blockIdx.x * 64;
  const int tid = threadIdx.x;
#pragma unroll
  for (int it = 0; it < 2; ++it) {
    const int idx = it * 256 + tid;      // 0..511
    const int r   = idx >> 3;            // n-local
    const int c8  = (idx & 7) * 8;       // d-local
    short8 v = *(const short8*)&I[(size_t)(n0 + r) * 512 + d0 + c8];
#pragma unroll
    for (int j = 0; j < 8; j++) t[r][c8 + j] = ((const __hip_bfloat16*)&v)[j];
  }
  __syncthreads();
#pragma unroll
  for (int it = 0; it < 2; ++it) {
    const int idx = it * 256 + tid;
    const int dr  = idx >> 3;            // d-local
    const int n8  = (idx & 7) * 8;       // n-local
    short8 v;
#pragma unroll
    for (int j = 0; j < 8; j++) ((__hip_bfloat16*)&v)[j] = t[n8 + j][dr];
    *(short8*)&O[(size_t)(d0 + dr) * 4096 + n0 + n8] = v;
  }
}

extern "C" void kernel_launch(void* const* d_in, const int* in_sizes, int n_in,
                              void* d_out, int out_size, void* d_ws, size_t ws_size,
                              hipStream_t stream) {
  const float* X   = (const float*)d_in[0];
  const float* W1a = (const float*)d_in[1];
  const float* b1a = (const float*)d_in[2];
  const float* W1b = (const float*)d_in[3];
  const float* b1b = (const float*)d_in[4];
  const float* W2a = (const float*)d_in[5];
  const float* b2a = (const float*)d_in[6];
  const float* W2b = (const float*)d_in[7];
  const float* b2b = (const float*)d_in[8];
  float* Y = (float*)d_out;

  char* ws = (char*)d_ws;
  const size_t SZ = 33554432;  // 32768*512*2 bytes (16.78M bf16)
  __hip_bfloat16* Xb   = (__hip_bfloat16*)(ws);                 // [8,4096,512] bf16
  __hip_bfloat16* H    = (__hip_bfloat16*)(ws + SZ);            // scratch [32768,512] (H1/H2/XT)
  __hip_bfloat16* W1T  = (__hip_bfloat16*)(ws + 2 * SZ);        // [8][512][4096]; later reused as W2
  __hip_bfloat16* AT   = (__hip_bfloat16*)(ws + 3 * SZ);        // [8][512][512]
  __hip_bfloat16* Wb   = (__hip_bfloat16*)(ws + 3 * SZ + 4194304); // 4x[512,512] bf16
  __hip_bfloat16* W1ab = Wb;
  __hip_bfloat16* W1bb = Wb + 262144;
  __hip_bfloat16* W2ab = Wb + 2 * 262144;
  __hip_bfloat16* W2bb = Wb + 3 * 262144;

  dim3 blk(256);

  // 0) fp32 -> bf16 conversions
  cvt_f32_bf16<<<8192, blk, 0, stream>>>(X,   Xb,   16777216L);
  cvt_f32_bf16<<<128,  blk, 0, stream>>>(W1a, W1ab, 262144L);
  cvt_f32_bf16<<<128,  blk, 0, stream>>>(W1b, W1bb, 262144L);
  cvt_f32_bf16<<<128,  blk, 0, stream>>>(W2a, W2ab, 262144L);
  cvt_f32_bf16<<<128,  blk, 0, stream>>>(W2b, W2bb, 262144L);

  // 1) H1 = GELU(Xb @ W1a^T + b1a)            [32768,512] bf16
  gemm_nt<true, true, false, false><<<dim3(4, 256, 1), blk, 0, stream>>>(
      Xb, W1ab, b1a, H, 32768, 512, 512, 0, 0, 0);
  // 2) W1T[b][p][n] = H1 @ W1b^T + b1b (transposed store)
  gemm_nt<false, true, true, false><<<dim3(4, 256, 1), blk, 0, stream>>>(
      H, W1bb, b1b, W1T, 32768, 512, 512, 0, 0, 0);
  // 3) XT = transpose(Xb) -> H (H1 dead)
  __hip_bfloat16* XT = H;
  transpose_xt<<<dim3(8, 64, 8), blk, 0, stream>>>(Xb, XT);
  // 4) AT[b][d][p] = GELU(XT @ W1T^T) per batch (= GELU(P)^T), K=4096
  gemm_nt<true, false, false, false><<<dim3(4, 4, 8), blk, 0, stream>>>(
      XT, W1T, nullptr, AT, 512, 512, 4096,
      512L * 4096, 512L * 4096, 512L * 512);
  // 5) H2 = GELU(Xb @ W2a^T + b2a) -> H (XT dead)
  gemm_nt<true, true, false, false><<<dim3(4, 256, 1), blk, 0, stream>>>(
      Xb, W2ab, b2a, H, 32768, 512, 512, 0, 0, 0);
  // 6) W2 = H2 @ W2b^T + b2b -> reuse W1T buffer (W1T dead)
  __hip_bfloat16* W2m = W1T;
  gemm_nt<false, true, false, false><<<dim3(4, 256, 1), blk, 0, stream>>>(
      H, W2bb, b2b, W2m, 32768, 512, 512, 0, 0, 0);
  // 7) Y = W2 @ AT^T per batch -> fp32 out    [4096,512]
  gemm_nt<false, false, false, true><<<dim3(4, 32, 8), blk, 0, stream>>>(
      W2m, AT, nullptr, Y, 4096, 512, 512,
      4096L * 512, 512L * 512, 4096L * 512);
}

// Round 3
// 278.375 us; speedup vs baseline: 1.1332x; 1.1332x over previous
//
#include <hip/hip_runtime.h>
#include <hip/hip_bf16.h>

typedef __attribute__((ext_vector_type(8))) short short8;
typedef __attribute__((ext_vector_type(4))) float floatx4;

__device__ __forceinline__ void gload_lds16(const void* g, void* l) {
  __builtin_amdgcn_global_load_lds(
      (const __attribute__((address_space(1))) void*)g,
      (__attribute__((address_space(3))) void*)l, 16, 0, 0);
}

__device__ __forceinline__ float gelu_exact(float x) {
  return 0.5f * x * (1.0f + erff(x * 0.70710678118654752f));
}

#define BM 128
#define BN 128
#define BK 64

// C[M,N] = epilogue(A[M,K(stride)] @ B[N,K]^T + bias)   A,B bf16; bias fp32
// K = row stride (elements); Klen = reduction length this launch (<= K)
// STORE_T: write C transposed per 4096-row batch: CT[b][col][row%4096] (bf16)
// OUT_F32: write C as float (normal layout)
// SPLITK : blockIdx.z encodes (batch<<3)|kchunk; A,B offset by batch*s + kc*Klen;
//          C offset by blockIdx.z * sC (partials, bf16)
template<bool GELU_OUT, bool HASBIAS, bool STORE_T, bool OUT_F32, bool SPLITK>
__global__ __launch_bounds__(256, 2)
void gemm_nt(const __hip_bfloat16* __restrict__ Ag,
             const __hip_bfloat16* __restrict__ Bg,
             const float* __restrict__ bias,
             void* __restrict__ Cg,
             int M, int N, int K, int Klen,
             long sA, long sB, long sC)
{
  const long za = (long)blockIdx.z;
  const __hip_bfloat16* A;
  const __hip_bfloat16* B;
  if (SPLITK) {
    const long b  = za >> 3;
    const long kc = za & 7;
    A = Ag + b * sA + kc * Klen;
    B = Bg + b * sB + kc * Klen;
  } else {
    A = Ag + za * sA;
    B = Bg + za * sB;
  }

  __shared__ __align__(16) __hip_bfloat16 As[BM * BK];
  __shared__ __align__(16) __hip_bfloat16 Bs[BN * BK];

  const int tid  = threadIdx.x;
  const int lane = tid & 63;
  const int wid  = tid >> 6;   // 0..3
  const int wr   = wid >> 1;   // wave row 0..1
  const int wc   = wid & 1;    // wave col 0..1
  const int brow = blockIdx.y * BM;
  const int bcol = blockIdx.x * BN;

  floatx4 acc[4][4];
#pragma unroll
  for (int i = 0; i < 4; i++)
#pragma unroll
    for (int j = 0; j < 4; j++) acc[i][j] = (floatx4){0.f, 0.f, 0.f, 0.f};

  const int r_lo = lane >> 3;        // row within an 8-row group
  const int c8   = (lane & 7) * 8;   // k-offset (elements)

  const int ksteps = Klen / BK;
  for (int kt = 0; kt < ksteps; ++kt) {
    const int k0 = kt * BK;
#pragma unroll
    for (int r = 0; r < 4; ++r) {
      const int grp = r * 4 + wid;       // 16 groups of 8 rows
      const int row = grp * 8 + r_lo;
      gload_lds16(A + (size_t)(brow + row) * K + k0 + c8,
                  (void*)(As + grp * 512 + lane * 8));
      gload_lds16(B + (size_t)(bcol + row) * K + k0 + c8,
                  (void*)(Bs + grp * 512 + lane * 8));
    }
    __syncthreads();
#pragma unroll
    for (int kk = 0; kk < 2; ++kk) {
      short8 a[4], b[4];
#pragma unroll
      for (int i = 0; i < 4; i++)
        a[i] = *(const short8*)(As + (wr * 64 + i * 16 + (lane & 15)) * BK + kk * 32 + (lane >> 4) * 8);
#pragma unroll
      for (int j = 0; j < 4; j++)
        b[j] = *(const short8*)(Bs + (wc * 64 + j * 16 + (lane & 15)) * BK + kk * 32 + (lane >> 4) * 8);
#pragma unroll
      for (int i = 0; i < 4; i++)
#pragma unroll
        for (int j = 0; j < 4; j++)
          acc[i][j] = __builtin_amdgcn_mfma_f32_16x16x32_bf16(a[i], b[j], acc[i][j], 0, 0, 0);
    }
    __syncthreads();
  }

  // epilogue: C/D layout col=lane&15, row=(lane>>4)*4+reg
#pragma unroll
  for (int i = 0; i < 4; i++) {
    const int row0 = brow + wr * 64 + i * 16 + (lane >> 4) * 4;
#pragma unroll
    for (int j = 0; j < 4; j++) {
      const int col = bcol + wc * 64 + j * 16 + (lane & 15);
      float bv = 0.f;
      if (HASBIAS) bv = bias[col];
#pragma unroll
      for (int r = 0; r < 4; r++) {
        const int row = row0 + r;
        float v = acc[i][j][r] + bv;
        if (GELU_OUT) v = gelu_exact(v);
        if (OUT_F32) {
          ((float*)Cg + za * sC)[(size_t)row * N + col] = v;
        } else if (STORE_T) {
          const int bb = row >> 12;          // batch = row/4096
          const int n  = row & 4095;
          ((__hip_bfloat16*)Cg)[(size_t)bb * N * 4096 + (size_t)col * 4096 + n] = __float2bfloat16(v);
        } else {
          ((__hip_bfloat16*)Cg + za * sC)[(size_t)row * N + col] = __float2bfloat16(v);
        }
      }
    }
  }
}

// fp32 -> bf16, 8 elements/thread; n must be divisible by 8
__global__ __launch_bounds__(256)
void cvt_f32_bf16(const float* __restrict__ in, __hip_bfloat16* __restrict__ out, long n) {
  long i = ((long)blockIdx.x * 256 + threadIdx.x) * 8;
  if (i >= n) return;
  float4 v0 = *(const float4*)(in + i);
  float4 v1 = *(const float4*)(in + i + 4);
  short8 o;
  __hip_bfloat16* ob = (__hip_bfloat16*)&o;
  ob[0] = __float2bfloat16(v0.x); ob[1] = __float2bfloat16(v0.y);
  ob[2] = __float2bfloat16(v0.z); ob[3] = __float2bfloat16(v0.w);
  ob[4] = __float2bfloat16(v1.x); ob[5] = __float2bfloat16(v1.y);
  ob[6] = __float2bfloat16(v1.z); ob[7] = __float2bfloat16(v1.w);
  *(short8*)(out + i) = o;
}

// Xb [B][4096][512] bf16 -> XT [B][512][4096] bf16
__global__ __launch_bounds__(256)
void transpose_xt(const __hip_bfloat16* __restrict__ in,
                  __hip_bfloat16* __restrict__ out)
{
  __shared__ __hip_bfloat16 t[64][72];
  const int b  = blockIdx.z;
  const __hip_bfloat16* I = in  + (size_t)b * 4096 * 512;
  __hip_bfloat16*       O = out + (size_t)b * 512 * 4096;
  const int n0 = blockIdx.y * 64;
  const int d0 = blockIdx.x * 64;
  const int tid = threadIdx.x;
#pragma unroll
  for (int it = 0; it < 2; ++it) {
    const int idx = it * 256 + tid;      // 0..511
    const int r   = idx >> 3;            // n-local
    const int c8  = (idx & 7) * 8;       // d-local
    short8 v = *(const short8*)&I[(size_t)(n0 + r) * 512 + d0 + c8];
#pragma unroll
    for (int j = 0; j < 8; j++) t[r][c8 + j] = ((const __hip_bfloat16*)&v)[j];
  }
  __syncthreads();
#pragma unroll
  for (int it = 0; it < 2; ++it) {
    const int idx = it * 256 + tid;
    const int dr  = idx >> 3;            // d-local
    const int n8  = (idx & 7) * 8;       // n-local
    short8 v;
#pragma unroll
    for (int j = 0; j < 8; j++) ((__hip_bfloat16*)&v)[j] = t[n8 + j][dr];
    *(short8*)&O[(size_t)(d0 + dr) * 4096 + n0 + n8] = v;
  }
}

// AT[b][i] = bf16(GELU(sum_kc part[(b*8+kc)][i])), i in [0, 512*512)
__global__ __launch_bounds__(256)
void reduce_gelu_bf16(const __hip_bfloat16* __restrict__ part,
                      __hip_bfloat16* __restrict__ AT) {
  const long o = ((long)blockIdx.x * 256 + threadIdx.x) * 8;  // output elem idx
  const long b = o >> 18;          // 262144 = 2^18 elems per batch
  const long i = o & 262143;
  float s[8] = {0.f, 0.f, 0.f, 0.f, 0.f, 0.f, 0.f, 0.f};
#pragma unroll
  for (int kc = 0; kc < 8; kc++) {
    short8 v = *(const short8*)(part + (((b << 3) + kc) << 18) + i);
#pragma unroll
    for (int j = 0; j < 8; j++) s[j] += __bfloat162float(((const __hip_bfloat16*)&v)[j]);
  }
  short8 o8;
#pragma unroll
  for (int j = 0; j < 8; j++)
    ((__hip_bfloat16*)&o8)[j] = __float2bfloat16(gelu_exact(s[j]));
  *(short8*)(AT + o) = o8;
}

extern "C" void kernel_launch(void* const* d_in, const int* in_sizes, int n_in,
                              void* d_out, int out_size, void* d_ws, size_t ws_size,
                              hipStream_t stream) {
  const float* X   = (const float*)d_in[0];
  const float* W1a = (const float*)d_in[1];
  const float* b1a = (const float*)d_in[2];
  const float* W1b = (const float*)d_in[3];
  const float* b1b = (const float*)d_in[4];
  const float* W2a = (const float*)d_in[5];
  const float* b2a = (const float*)d_in[6];
  const float* W2b = (const float*)d_in[7];
  const float* b2b = (const float*)d_in[8];
  float* Y = (float*)d_out;

  char* ws = (char*)d_ws;
  const size_t SZ = 33554432;  // 32768*512*2 bytes (16.78M bf16)
  __hip_bfloat16* Xb   = (__hip_bfloat16*)(ws);                 // [8,4096,512] bf16; later split-K partials [64][512][512]
  __hip_bfloat16* H    = (__hip_bfloat16*)(ws + SZ);            // [32768,512] (H1, then H2)
  __hip_bfloat16* W1T  = (__hip_bfloat16*)(ws + 2 * SZ);        // [8][512][4096]; later W2m
  __hip_bfloat16* XT   = (__hip_bfloat16*)(ws + 3 * SZ);        // [8][512][4096]
  __hip_bfloat16* AT   = (__hip_bfloat16*)(ws + 4 * SZ);        // [8][512][512]
  __hip_bfloat16* Wb   = (__hip_bfloat16*)(ws + 4 * SZ + 4194304); // 4x[512,512] bf16
  __hip_bfloat16* W1ab = Wb;
  __hip_bfloat16* W1bb = Wb + 262144;
  __hip_bfloat16* W2ab = Wb + 2 * 262144;
  __hip_bfloat16* W2bb = Wb + 3 * 262144;

  dim3 blk(256);

  // 0) fp32 -> bf16 conversions
  cvt_f32_bf16<<<8192, blk, 0, stream>>>(X,   Xb,   16777216L);
  cvt_f32_bf16<<<128,  blk, 0, stream>>>(W1a, W1ab, 262144L);
  cvt_f32_bf16<<<128,  blk, 0, stream>>>(W1b, W1bb, 262144L);
  cvt_f32_bf16<<<128,  blk, 0, stream>>>(W2a, W2ab, 262144L);
  cvt_f32_bf16<<<128,  blk, 0, stream>>>(W2b, W2bb, 262144L);

  // 1) H1 = GELU(Xb @ W1a^T + b1a)            [32768,512] bf16 -> H
  gemm_nt<true, true, false, false, false><<<dim3(4, 256, 1), blk, 0, stream>>>(
      Xb, W1ab, b1a, H, 32768, 512, 512, 512, 0, 0, 0);
  // 2) W1T[b][p][n] = H1 @ W1b^T + b1b (transposed store)
  gemm_nt<false, true, true, false, false><<<dim3(4, 256, 1), blk, 0, stream>>>(
      H, W1bb, b1b, W1T, 32768, 512, 512, 512, 0, 0, 0);
  // 3) XT = transpose(Xb)
  transpose_xt<<<dim3(8, 64, 8), blk, 0, stream>>>(Xb, XT);
  // 4) H2 = GELU(Xb @ W2a^T + b2a) -> H (H1 dead; Xb dead after this)
  gemm_nt<true, true, false, false, false><<<dim3(4, 256, 1), blk, 0, stream>>>(
      Xb, W2ab, b2a, H, 32768, 512, 512, 512, 0, 0, 0);
  // 5) split-K: partials[z][d][p] = XT[b] @ W1T[b]^T over k-chunk kc (z=b*8+kc)
  __hip_bfloat16* part = Xb;  // reuse (Xb dead)
  gemm_nt<false, false, false, false, true><<<dim3(4, 4, 64), blk, 0, stream>>>(
      XT, W1T, nullptr, part, 512, 512, 4096, 512,
      512L * 4096, 512L * 4096, 262144L);
  // 6) AT[b][d][p] = GELU(sum_kc part) -> AT
  reduce_gelu_bf16<<<1024, blk, 0, stream>>>(part, AT);
  // 7) W2m = H2 @ W2b^T + b2b -> reuse W1T buffer (W1T dead after step 5)
  __hip_bfloat16* W2m = W1T;
  gemm_nt<false, true, false, false, false><<<dim3(4, 256, 1), blk, 0, stream>>>(
      H, W2bb, b2b, W2m, 32768, 512, 512, 512, 0, 0, 0);
  // 8) Y = W2m @ AT^T per batch -> fp32 out   [4096,512]
  gemm_nt<false, false, false, true, false><<<dim3(4, 32, 8), blk, 0, stream>>>(
      W2m, AT, nullptr, Y, 4096, 512, 512, 512,
      4096L * 512, 512L * 512, 4096L * 512);
}

// Round 4
// 252.932 us; speedup vs baseline: 1.2472x; 1.1006x over previous
//
#include <hip/hip_runtime.h>
#include <hip/hip_bf16.h>

typedef __attribute__((ext_vector_type(8))) short short8;
typedef __attribute__((ext_vector_type(4))) short short4v;
typedef __attribute__((ext_vector_type(4))) float floatx4;

__device__ __forceinline__ void gload_lds16(const void* g, void* l) {
  __builtin_amdgcn_global_load_lds(
      (const __attribute__((address_space(1))) void*)g,
      (__attribute__((address_space(3))) void*)l, 16, 0, 0);
}

__device__ __forceinline__ float gelu_exact(float x) {
  return 0.5f * x * (1.0f + erff(x * 0.70710678118654752f));
}

#define BM 128
#define BN 128
#define BK 64

// C[M,N] = epilogue(A[M,K(stride)] @ B[N,K]^T + bias)   A,B bf16; bias fp32
// K = row stride (elements); Klen = reduction length this launch (<= K)
// STORE_T: write C transposed per 4096-row batch: CT[b][col][row%4096] (bf16)
// OUT_F32: write C as float (normal layout)
// SPLITK : logical z encodes (batch<<3)|kchunk; A,B offset by batch*s + kc*Klen;
//          C offset by z * sC (partials, bf16)
// SWZ: 0 none; 1 chunked XCD (same-A-panel blocks -> same XCD);
//      2 P-custom (grid must be (4,4,64): 16 blocks sharing (b,kc) -> same XCD)
template<bool GELU_OUT, bool HASBIAS, bool STORE_T, bool OUT_F32, bool SPLITK, int SWZ>
__global__ __launch_bounds__(256, 2)
void gemm_nt(const __hip_bfloat16* __restrict__ Ag,
             const __hip_bfloat16* __restrict__ Bg,
             const float* __restrict__ bias,
             void* __restrict__ Cg,
             int M, int N, int K, int Klen,
             long sA, long sB, long sC)
{
  int bx, by, bz;
  if (SWZ == 1) {
    const int gx = gridDim.x, gy = gridDim.y;
    const int total = gx * gy * gridDim.z;   // must be divisible by 8
    const int f = blockIdx.x + gx * (blockIdx.y + gy * blockIdx.z);
    const int l = (f & 7) * (total >> 3) + (f >> 3);
    bx = l % gx;
    const int rr = l / gx;
    by = rr % gy;
    bz = rr / gy;
  } else if (SWZ == 2) {
    const int f = blockIdx.x + 4 * blockIdx.y + 16 * blockIdx.z;
    const int xcd = f & 7, s = f >> 3;
    bz = xcd + 8 * (s >> 4);       // (b,kc) group -> one XCD
    const int t = s & 15;
    by = t >> 2;
    bx = t & 3;
  } else {
    bx = blockIdx.x; by = blockIdx.y; bz = blockIdx.z;
  }

  const long za = (long)bz;
  const __hip_bfloat16* A;
  const __hip_bfloat16* B;
  if (SPLITK) {
    const long b  = za >> 3;
    const long kc = za & 7;
    A = Ag + b * sA + kc * Klen;
    B = Bg + b * sB + kc * Klen;
  } else {
    A = Ag + za * sA;
    B = Bg + za * sB;
  }

  __shared__ __align__(16) __hip_bfloat16 As[BM * BK];
  __shared__ __align__(16) __hip_bfloat16 Bs[BN * BK];

  const int tid  = threadIdx.x;
  const int lane = tid & 63;
  const int wid  = tid >> 6;   // 0..3
  const int wr   = wid >> 1;   // wave row 0..1
  const int wc   = wid & 1;    // wave col 0..1
  const int brow = by * BM;
  const int bcol = bx * BN;

  floatx4 acc[4][4];
#pragma unroll
  for (int i = 0; i < 4; i++)
#pragma unroll
    for (int j = 0; j < 4; j++) acc[i][j] = (floatx4){0.f, 0.f, 0.f, 0.f};

  const int r_lo = lane >> 3;        // row within an 8-row group
  const int c8   = (lane & 7) * 8;   // k-offset (elements)

  const int ksteps = Klen / BK;
  for (int kt = 0; kt < ksteps; ++kt) {
    const int k0 = kt * BK;
#pragma unroll
    for (int r = 0; r < 4; ++r) {
      const int grp = r * 4 + wid;       // 16 groups of 8 rows
      const int row = grp * 8 + r_lo;
      gload_lds16(A + (size_t)(brow + row) * K + k0 + c8,
                  (void*)(As + grp * 512 + lane * 8));
      gload_lds16(B + (size_t)(bcol + row) * K + k0 + c8,
                  (void*)(Bs + grp * 512 + lane * 8));
    }
    __syncthreads();
#pragma unroll
    for (int kk = 0; kk < 2; ++kk) {
      short8 a[4], b[4];
#pragma unroll
      for (int i = 0; i < 4; i++)
        a[i] = *(const short8*)(As + (wr * 64 + i * 16 + (lane & 15)) * BK + kk * 32 + (lane >> 4) * 8);
#pragma unroll
      for (int j = 0; j < 4; j++)
        b[j] = *(const short8*)(Bs + (wc * 64 + j * 16 + (lane & 15)) * BK + kk * 32 + (lane >> 4) * 8);
#pragma unroll
      for (int i = 0; i < 4; i++)
#pragma unroll
        for (int j = 0; j < 4; j++)
          acc[i][j] = __builtin_amdgcn_mfma_f32_16x16x32_bf16(a[i], b[j], acc[i][j], 0, 0, 0);
    }
    __syncthreads();
  }

  // epilogue: C/D layout col=lane&15, row=(lane>>4)*4+reg
#pragma unroll
  for (int i = 0; i < 4; i++) {
    const int row0 = brow + wr * 64 + i * 16 + (lane >> 4) * 4;
#pragma unroll
    for (int j = 0; j < 4; j++) {
      const int col = bcol + wc * 64 + j * 16 + (lane & 15);
      float bv = 0.f;
      if (HASBIAS) bv = bias[col];
#pragma unroll
      for (int r = 0; r < 4; r++) {
        const int row = row0 + r;
        float v = acc[i][j][r] + bv;
        if (GELU_OUT) v = gelu_exact(v);
        if (OUT_F32) {
          ((float*)Cg + za * sC)[(size_t)row * N + col] = v;
        } else if (STORE_T) {
          const int bb = row >> 12;          // batch = row/4096
          const int n  = row & 4095;
          ((__hip_bfloat16*)Cg)[(size_t)bb * N * 4096 + (size_t)col * 4096 + n] = __float2bfloat16(v);
        } else {
          ((__hip_bfloat16*)Cg + za * sC)[(size_t)row * N + col] = __float2bfloat16(v);
        }
      }
    }
  }
}

// fp32 -> bf16, 8 elements/thread; n must be divisible by 8
__global__ __launch_bounds__(256)
void cvt_f32_bf16(const float* __restrict__ in, __hip_bfloat16* __restrict__ out, long n) {
  long i = ((long)blockIdx.x * 256 + threadIdx.x) * 8;
  if (i >= n) return;
  float4 v0 = *(const float4*)(in + i);
  float4 v1 = *(const float4*)(in + i + 4);
  short8 o;
  __hip_bfloat16* ob = (__hip_bfloat16*)&o;
  ob[0] = __float2bfloat16(v0.x); ob[1] = __float2bfloat16(v0.y);
  ob[2] = __float2bfloat16(v0.z); ob[3] = __float2bfloat16(v0.w);
  ob[4] = __float2bfloat16(v1.x); ob[5] = __float2bfloat16(v1.y);
  ob[6] = __float2bfloat16(v1.z); ob[7] = __float2bfloat16(v1.w);
  *(short8*)(out + i) = o;
}

// X fp32 [B][4096][512] -> Xb bf16 [B][4096][512]  AND  XT bf16 [B][512][4096]
// grid (8 d-tiles, 64 n-tiles, 8 batches), 64x64 tiles
__global__ __launch_bounds__(256)
void cvt_x_xt(const float* __restrict__ X,
              __hip_bfloat16* __restrict__ Xb,
              __hip_bfloat16* __restrict__ XT)
{
  __shared__ __hip_bfloat16 t[64][66];   // odd-dword row stride: ~conflict-free transpose reads
  const int b  = blockIdx.z;
  const int n0 = blockIdx.y * 64;
  const int d0 = blockIdx.x * 64;
  const float* I = X + (size_t)b * 4096 * 512;
  __hip_bfloat16* XB = Xb + (size_t)b * 4096 * 512;
  __hip_bfloat16* XO = XT + (size_t)b * 512 * 4096;
  const int tid = threadIdx.x;
#pragma unroll
  for (int it = 0; it < 4; ++it) {
    const int idx = it * 256 + tid;      // 0..1023
    const int r   = idx >> 4;            // n-local 0..63
    const int c4  = (idx & 15) * 4;      // d-local 0..60
    float4 v = *(const float4*)&I[(size_t)(n0 + r) * 512 + d0 + c4];
    short4v o;
    __hip_bfloat16* ob = (__hip_bfloat16*)&o;
    ob[0] = __float2bfloat16(v.x); ob[1] = __float2bfloat16(v.y);
    ob[2] = __float2bfloat16(v.z); ob[3] = __float2bfloat16(v.w);
    t[r][c4]     = ob[0]; t[r][c4 + 1] = ob[1];
    t[r][c4 + 2] = ob[2]; t[r][c4 + 3] = ob[3];
    *(short4v*)&XB[(size_t)(n0 + r) * 512 + d0 + c4] = o;
  }
  __syncthreads();
#pragma unroll
  for (int it = 0; it < 4; ++it) {
    const int idx = it * 256 + tid;
    const int dr  = idx >> 4;            // d-local 0..63
    const int n4  = (idx & 15) * 4;      // n-local 0..60
    short4v o;
    __hip_bfloat16* ob = (__hip_bfloat16*)&o;
#pragma unroll
    for (int j = 0; j < 4; j++) ob[j] = t[n4 + j][dr];
    *(short4v*)&XO[(size_t)(d0 + dr) * 4096 + n0 + n4] = o;
  }
}

// AT[b][i] = bf16(GELU(sum_kc part[(b*8+kc)][i])), i in [0, 512*512)
__global__ __launch_bounds__(256)
void reduce_gelu_bf16(const __hip_bfloat16* __restrict__ part,
                      __hip_bfloat16* __restrict__ AT) {
  const long o = ((long)blockIdx.x * 256 + threadIdx.x) * 8;  // output elem idx
  const long b = o >> 18;          // 262144 = 2^18 elems per batch
  const long i = o & 262143;
  float s[8] = {0.f, 0.f, 0.f, 0.f, 0.f, 0.f, 0.f, 0.f};
#pragma unroll
  for (int kc = 0; kc < 8; kc++) {
    short8 v = *(const short8*)(part + (((b << 3) + kc) << 18) + i);
#pragma unroll
    for (int j = 0; j < 8; j++) s[j] += __bfloat162float(((const __hip_bfloat16*)&v)[j]);
  }
  short8 o8;
#pragma unroll
  for (int j = 0; j < 8; j++)
    ((__hip_bfloat16*)&o8)[j] = __float2bfloat16(gelu_exact(s[j]));
  *(short8*)(AT + o) = o8;
}

extern "C" void kernel_launch(void* const* d_in, const int* in_sizes, int n_in,
                              void* d_out, int out_size, void* d_ws, size_t ws_size,
                              hipStream_t stream) {
  const float* X   = (const float*)d_in[0];
  const float* W1a = (const float*)d_in[1];
  const float* b1a = (const float*)d_in[2];
  const float* W1b = (const float*)d_in[3];
  const float* b1b = (const float*)d_in[4];
  const float* W2a = (const float*)d_in[5];
  const float* b2a = (const float*)d_in[6];
  const float* W2b = (const float*)d_in[7];
  const float* b2b = (const float*)d_in[8];
  float* Y = (float*)d_out;

  char* ws = (char*)d_ws;
  const size_t SZ = 33554432;  // 32768*512*2 bytes
  __hip_bfloat16* Xb   = (__hip_bfloat16*)(ws);                 // [8,4096,512]; later split-K partials [64][512][512]
  __hip_bfloat16* H    = (__hip_bfloat16*)(ws + SZ);            // [32768,512] (H1, then H2)
  __hip_bfloat16* W1T  = (__hip_bfloat16*)(ws + 2 * SZ);        // [8][512][4096]; later W2m
  __hip_bfloat16* XT   = (__hip_bfloat16*)(ws + 3 * SZ);        // [8][512][4096]
  __hip_bfloat16* AT   = (__hip_bfloat16*)(ws + 4 * SZ);        // [8][512][512]
  __hip_bfloat16* Wb   = (__hip_bfloat16*)(ws + 4 * SZ + 4194304); // 4x[512,512] bf16
  __hip_bfloat16* W1ab = Wb;
  __hip_bfloat16* W1bb = Wb + 262144;
  __hip_bfloat16* W2ab = Wb + 2 * 262144;
  __hip_bfloat16* W2bb = Wb + 3 * 262144;

  dim3 blk(256);

  // 0) conversions; X also emits XT (fused transpose)
  cvt_f32_bf16<<<128,  blk, 0, stream>>>(W1a, W1ab, 262144L);
  cvt_f32_bf16<<<128,  blk, 0, stream>>>(W1b, W1bb, 262144L);
  cvt_f32_bf16<<<128,  blk, 0, stream>>>(W2a, W2ab, 262144L);
  cvt_f32_bf16<<<128,  blk, 0, stream>>>(W2b, W2bb, 262144L);
  cvt_x_xt<<<dim3(8, 64, 8), blk, 0, stream>>>(X, Xb, XT);

  // 1) H1 = GELU(Xb @ W1a^T + b1a)            [32768,512] bf16 -> H
  gemm_nt<true, true, false, false, false, 1><<<dim3(4, 256, 1), blk, 0, stream>>>(
      Xb, W1ab, b1a, H, 32768, 512, 512, 512, 0, 0, 0);
  // 2) W1T[b][p][n] = H1 @ W1b^T + b1b (transposed store)
  gemm_nt<false, true, true, false, false, 1><<<dim3(4, 256, 1), blk, 0, stream>>>(
      H, W1bb, b1b, W1T, 32768, 512, 512, 512, 0, 0, 0);
  // 3) H2 = GELU(Xb @ W2a^T + b2a) -> H (H1 consumed; Xb dead after this)
  gemm_nt<true, true, false, false, false, 1><<<dim3(4, 256, 1), blk, 0, stream>>>(
      Xb, W2ab, b2a, H, 32768, 512, 512, 512, 0, 0, 0);
  // 4) split-K: partials[z][d][p] = XT[b] @ W1T[b]^T over k-chunk kc (z=b*8+kc)
  __hip_bfloat16* part = Xb;  // reuse (Xb dead)
  gemm_nt<false, false, false, false, true, 2><<<dim3(4, 4, 64), blk, 0, stream>>>(
      XT, W1T, nullptr, part, 512, 512, 4096, 512,
      512L * 4096, 512L * 4096, 262144L);
  // 5) AT[b][d][p] = GELU(sum_kc part) -> AT
  reduce_gelu_bf16<<<1024, blk, 0, stream>>>(part, AT);
  // 6) W2m = H2 @ W2b^T + b2b -> reuse W1T buffer (W1T dead after step 4)
  __hip_bfloat16* W2m = W1T;
  gemm_nt<false, true, false, false, false, 1><<<dim3(4, 256, 1), blk, 0, stream>>>(
      H, W2bb, b2b, W2m, 32768, 512, 512, 512, 0, 0, 0);
  // 7) Y = W2m @ AT^T per batch -> fp32 out   [4096,512]
  gemm_nt<false, false, false, true, false, 1><<<dim3(4, 32, 8), blk, 0, stream>>>(
      W2m, AT, nullptr, Y, 4096, 512, 512, 512,
      4096L * 512, 512L * 512, 4096L * 512);
}